// Round 1
// 329.162 us; speedup vs baseline: 1.8173x; 1.8173x over previous
//
#include <hip/hip_runtime.h>
#include <stdint.h>

#define T_LEN 2048
#define B_TOT 64
#define N_TAG 128
#define MID 1024  // fwd applies M_1..M_{MID-1}; bwd applies M'_{MID}..M'_{T-1}

typedef __attribute__((ext_vector_type(4))) float f32x4;
typedef __attribute__((ext_vector_type(8))) short bf16x8;
typedef __attribute__((ext_vector_type(4))) uint32_t u32x4;
typedef __attribute__((ext_vector_type(2))) uint32_t u32x2;

template <int S>
struct IC {
  static constexpr int value = S;
};

// mid-boundary handoff (written by scan, read by combine; kernel-boundary
// release/acquire gives cross-XCD visibility on same stream)
__device__ __align__(16) float g_alpha[B_TOT][N_TAG];
__device__ __align__(16) float g_v[B_TOT][N_TAG];
__device__ float g_Lf[B_TOT];
__device__ float g_Lb[B_TOT];

// pack two fp32 -> dword of two bf16 (round-half-up); elem0 in low half
__device__ __forceinline__ uint32_t pack2_bf16(float a, float b) {
  uint32_t ua = __float_as_uint(a) + 0x8000u;
  uint32_t ub = __float_as_uint(b) + 0x8000u;
  return __builtin_amdgcn_perm(ua, ub, 0x03020706u);
}
__device__ __forceinline__ float bf_lo(uint32_t w) {
  return __uint_as_float(w << 16);
}
__device__ __forceinline__ float bf_hi(uint32_t w) {
  return __uint_as_float(w & 0xffff0000u);
}

// prepass: ws[t][b][i] = bf16(exp(em[b][t][i])), i-pairs packed in u32
__global__ __launch_bounds__(256) void eem_prepass(const float* __restrict__ em,
                                                   uint32_t* __restrict__ ws) {
  const int tid = blockIdx.x * blockDim.x + threadIdx.x;  // 0 .. 2^21-1
  const int b = tid >> 15;
  const int rem = tid & 32767;
  const int t = rem >> 4;
  const int kk = rem & 15;  // 8 floats per thread
  const float4* src =
      (const float4*)(em + ((size_t)b * T_LEN + t) * N_TAG + kk * 8);
  const float4 p0 = src[0];
  const float4 p1 = src[1];
  u32x4 o;
  o[0] = pack2_bf16(__expf(p0.x), __expf(p0.y));
  o[1] = pack2_bf16(__expf(p0.z), __expf(p0.w));
  o[2] = pack2_bf16(__expf(p1.x), __expf(p1.y));
  o[3] = pack2_bf16(__expf(p1.z), __expf(p1.w));
  *(u32x4*)(ws + ((size_t)t * B_TOT + b) * (N_TAG / 2) + kk * 4) = o;
}

// Two-ended scan: blocks 0-3 run the forward half (t = 1 .. MID-1, maskless
// since setup guarantees len >= 1024), blocks 4-7 run the backward half
// (t = T-1 .. MID, with per-lane identity select for t >= len). Each half
// keeps the verified 8-wave structure: wave w owns 16 j's, A rows permuted so
// the f32x4 D output IS the half-fragment of next step's B operand
// (1 ds_write_b64 + 4 ds_read_b128 per wave per step). Backward folds the
// emission multiply producer-side: LDS carries u_t = e_t (*) v_{t+1}, while
// each wave keeps its v share in f32 registers for the identity select.
__global__ __launch_bounds__(512, 2) void crf_scan_kernel(
    const float* __restrict__ em, const int* __restrict__ lens,
    const float* __restrict__ trans, const float* __restrict__ head,
    const float* __restrict__ last, const uint32_t* __restrict__ eem) {
  const int lane = threadIdx.x & 63;
  const int w = threadIdx.x >> 6;  // 0..7
  const int f = w >> 1;            // owned fragment
  const int h = w & 1;             // half within fragment
  const int c = lane & 15;         // batch-in-tile
  const int q = lane >> 4;
  const bool is_fwd = (blockIdx.x < 4);
  const int bg = ((int)blockIdx.x & 3) * 16 + c;
  const int jbase = f * 32 + q * 8 + h * 4;  // lane's 4 state indices

  __shared__ uint32_t x_lds[2][4][64][4];  // [pingpong][frag][lane][dword]
  __shared__ int k_lds[16];

  const size_t eoff = (size_t)bg * 64 + f * 16 + q * 4 + h * 2;
  u32x2 eslot[4];
  auto issue_eem = [&](auto sc, int row) {
    constexpr int S = decltype(sc)::value;
    eslot[S] = *(const u32x2*)(eem + (size_t)row * 4096 + eoff);
  };

  const f32x4 vzero = {0.f, 0.f, 0.f, 0.f};

  if (is_fwd) {
    // ================= forward half: produce alpha_{MID-1} =================
    // A[m=j][k=i] = exp(trans[i][j]), rows permuted per wave
    bf16x8 efrag[4];
    {
      const int j = f * 32 + (c >> 2) * 8 + h * 4 + (c & 3);
#pragma unroll
      for (int ktv = 0; ktv < 4; ++ktv) {
        const int ktp = (w + ktv) & 3;
        u32x4 wd;
#pragma unroll
        for (int p = 0; p < 4; ++p) {
          const int i0 = ktp * 32 + q * 8 + 2 * p;
          wd[p] = pack2_bf16(__expf(trans[(i0 + 0) * N_TAG + j]),
                             __expf(trans[(i0 + 1) * N_TAG + j]));
        }
        efrag[ktv] = __builtin_bit_cast(bf16x8, wd);
      }
    }
    float L = 0.f;
    const float* emb = em + (size_t)bg * T_LEN * N_TAG;
    {
      float v0[4];
#pragma unroll
      for (int r = 0; r < 4; ++r)
        v0[r] = __expf(head[jbase + r] + emb[jbase + r]);
      u32x2 wd;
      wd[0] = pack2_bf16(v0[0], v0[1]);
      wd[1] = pack2_bf16(v0[2], v0[3]);
      *(u32x2*)&x_lds[0][f][lane][h * 2] = wd;
    }
    if (w == 0 && lane < 16) k_lds[lane] = 0;
    __syncthreads();

    issue_eem(IC<1>{}, 1);
    issue_eem(IC<2>{}, 2);
    issue_eem(IC<3>{}, 3);

    auto step = [&](auto slotc, int t) {
      constexpr int SLOT = decltype(slotc)::value;
      constexpr int RP = (SLOT + 1) & 1;
      constexpr int WP = SLOT & 1;
      {
        int row = t + 3;
        if (row > T_LEN - 1) row = T_LEN - 1;
        issue_eem(IC<(SLOT + 3) & 3>{}, row);
      }
      int e = 0;
      if (SLOT == 1) e = k_lds[c];
      u32x4 bfr[4];
#pragma unroll
      for (int ktv = 0; ktv < 4; ++ktv)
        bfr[ktv] = *(const u32x4*)&x_lds[RP][(w + ktv) & 3][lane][0];
      const u32x2 ev = eslot[SLOT];
      float ff[4];
      ff[0] = bf_lo(ev[0]);
      ff[1] = bf_hi(ev[0]);
      ff[2] = bf_lo(ev[1]);
      ff[3] = bf_hi(ev[1]);
      if (SLOT == 1) {
        const float sc = __uint_as_float((uint32_t)(127 - e) << 23);
#pragma unroll
        for (int r = 0; r < 4; ++r) ff[r] *= sc;
        L += (float)e * 0.6931471805599453f;
      }
      f32x4 acc = __builtin_amdgcn_mfma_f32_16x16x32_bf16(
          efrag[0], __builtin_bit_cast(bf16x8, bfr[0]), vzero, 0, 0, 0);
      acc = __builtin_amdgcn_mfma_f32_16x16x32_bf16(
          efrag[1], __builtin_bit_cast(bf16x8, bfr[1]), acc, 0, 0, 0);
      acc = __builtin_amdgcn_mfma_f32_16x16x32_bf16(
          efrag[2], __builtin_bit_cast(bf16x8, bfr[2]), acc, 0, 0, 0);
      acc = __builtin_amdgcn_mfma_f32_16x16x32_bf16(
          efrag[3], __builtin_bit_cast(bf16x8, bfr[3]), acc, 0, 0, 0);
      if (SLOT == 0) {
        if (w == 0 && lane < 16)
          k_lds[c] = (int)(__float_as_uint(acc[0]) >> 23) - 126;
      }
      if (t == MID - 1) {  // mid-boundary capture (full f32 precision)
#pragma unroll
        for (int r = 0; r < 4; ++r) g_alpha[bg][jbase + r] = acc[r] * ff[r];
        if (w == 0 && q == 0) g_Lf[bg] = L;
      }
      u32x2 wd;
      wd[0] = pack2_bf16(acc[0] * ff[0], acc[1] * ff[1]);
      wd[1] = pack2_bf16(acc[2] * ff[2], acc[3] * ff[3]);
      *(u32x2*)&x_lds[WP][f][lane][h * 2] = wd;
      __syncthreads();
    };

    int t = 1;
#pragma unroll 1
    for (int it = 0; it < 255; ++it) {  // t = 1 .. 1020
      step(IC<1>{}, t);
      step(IC<2>{}, t + 1);
      step(IC<3>{}, t + 2);
      step(IC<0>{}, t + 3);
      t += 4;
    }
    step(IC<1>{}, t);      // 1021
    step(IC<2>{}, t + 1);  // 1022
    step(IC<3>{}, t + 2);  // 1023 (capture)
  } else {
    // ================= backward half: produce v_MID =================
    // A[m=i][k=j] = exp(trans[i][j]) (untransposed), same row permutation
    bf16x8 efrag[4];
    {
      const int irow = f * 32 + (c >> 2) * 8 + h * 4 + (c & 3);
#pragma unroll
      for (int ktv = 0; ktv < 4; ++ktv) {
        const int ktp = (w + ktv) & 3;
        u32x4 wd;
#pragma unroll
        for (int p = 0; p < 4; ++p) {
          const int j0 = ktp * 32 + q * 8 + 2 * p;
          wd[p] = pack2_bf16(__expf(trans[irow * N_TAG + j0 + 0]),
                             __expf(trans[irow * N_TAG + j0 + 1]));
        }
        efrag[ktv] = __builtin_bit_cast(bf16x8, wd);
      }
    }
    const int mylen = lens[bg];
    float L = 0.f;
    float vprev[4];
    {
      // v_T = exp(last); LDS gets u_{T-1} = e_{T-1} (*) v_T
      const u32x2 ev0 =
          *(const u32x2*)(eem + (size_t)(T_LEN - 1) * 4096 + eoff);
#pragma unroll
      for (int r = 0; r < 4; ++r) vprev[r] = __expf(last[jbase + r]);
      u32x2 wd;
      wd[0] = pack2_bf16(vprev[0] * bf_lo(ev0[0]), vprev[1] * bf_hi(ev0[0]));
      wd[1] = pack2_bf16(vprev[2] * bf_lo(ev0[1]), vprev[3] * bf_hi(ev0[1]));
      *(u32x2*)&x_lds[0][f][lane][h * 2] = wd;
    }
    if (w == 0 && lane < 16) k_lds[lane] = 0;
    __syncthreads();

    issue_eem(IC<1>{}, T_LEN - 2);  // e_{t-1} for t = 2047
    issue_eem(IC<2>{}, T_LEN - 3);
    issue_eem(IC<3>{}, T_LEN - 4);

    auto step = [&](auto slotc, int t) {
      constexpr int SLOT = decltype(slotc)::value;
      constexpr int RP = (SLOT + 1) & 1;
      constexpr int WP = SLOT & 1;
      {
        int row = t - 4;
        if (row < 0) row = 0;
        issue_eem(IC<(SLOT + 3) & 3>{}, row);
      }
      int e = 0;
      if (SLOT == 1) e = k_lds[c];
      u32x4 bfr[4];
#pragma unroll
      for (int ktv = 0; ktv < 4; ++ktv)
        bfr[ktv] = *(const u32x4*)&x_lds[RP][(w + ktv) & 3][lane][0];
      const u32x2 ev = eslot[SLOT];  // e_{t-1}, for packing u_{t-1}
      float ee[4];
      ee[0] = bf_lo(ev[0]);
      ee[1] = bf_hi(ev[0]);
      ee[2] = bf_lo(ev[1]);
      ee[3] = bf_hi(ev[1]);
      f32x4 acc = __builtin_amdgcn_mfma_f32_16x16x32_bf16(
          efrag[0], __builtin_bit_cast(bf16x8, bfr[0]), vzero, 0, 0, 0);
      acc = __builtin_amdgcn_mfma_f32_16x16x32_bf16(
          efrag[1], __builtin_bit_cast(bf16x8, bfr[1]), acc, 0, 0, 0);
      acc = __builtin_amdgcn_mfma_f32_16x16x32_bf16(
          efrag[2], __builtin_bit_cast(bf16x8, bfr[2]), acc, 0, 0, 0);
      acc = __builtin_amdgcn_mfma_f32_16x16x32_bf16(
          efrag[3], __builtin_bit_cast(bf16x8, bfr[3]), acc, 0, 0, 0);
      // identity select for padded steps (t >= len): keep v unchanged
      const bool valid = (t < mylen);
      float vnew[4];
#pragma unroll
      for (int r = 0; r < 4; ++r) vnew[r] = valid ? acc[r] : vprev[r];
      if (SLOT == 1) {
        const float sc = __uint_as_float((uint32_t)(127 - e) << 23);
#pragma unroll
        for (int r = 0; r < 4; ++r) vnew[r] *= sc;
        L += (float)e * 0.6931471805599453f;
      }
      if (SLOT == 0) {
        if (w == 0 && lane < 16)
          k_lds[c] = (int)(__float_as_uint(vnew[0]) >> 23) - 126;
      }
      if (t == MID) {  // mid-boundary capture
#pragma unroll
        for (int r = 0; r < 4; ++r) g_v[bg][jbase + r] = vnew[r];
        if (w == 0 && q == 0) g_Lb[bg] = L;
      }
      u32x2 wd;
      wd[0] = pack2_bf16(vnew[0] * ee[0], vnew[1] * ee[1]);
      wd[1] = pack2_bf16(vnew[2] * ee[2], vnew[3] * ee[3]);
      *(u32x2*)&x_lds[WP][f][lane][h * 2] = wd;
#pragma unroll
      for (int r = 0; r < 4; ++r) vprev[r] = vnew[r];
      __syncthreads();
    };

    int t = T_LEN - 1;  // 2047
#pragma unroll 1
    for (int it = 0; it < 256; ++it) {  // t = 2047 .. 1024 (capture at 1024)
      step(IC<1>{}, t);
      step(IC<2>{}, t - 1);
      step(IC<3>{}, t - 2);
      step(IC<0>{}, t - 3);
      t -= 4;
    }
  }
}

// Z[b] = log(sum_j alpha[b][j] * v[b][j]) + Lf[b] + Lb[b]
__global__ __launch_bounds__(256) void crf_combine(float* __restrict__ out) {
  const int tid = threadIdx.x;  // 256 = 64 batches x 4 lanes
  const int b = tid >> 2;
  const int p = tid & 3;
  float s = 0.f;
#pragma unroll
  for (int k = 0; k < 8; ++k) {
    const f32x4 a = *(const f32x4*)&g_alpha[b][p * 32 + k * 4];
    const f32x4 v = *(const f32x4*)&g_v[b][p * 32 + k * 4];
    s += a[0] * v[0] + a[1] * v[1] + a[2] * v[2] + a[3] * v[3];
  }
  s += __shfl_xor(s, 1);
  s += __shfl_xor(s, 2);
  if (p == 0) out[b] = __logf(s) + g_Lf[b] + g_Lb[b];
}

extern "C" void kernel_launch(void* const* d_in, const int* in_sizes, int n_in,
                              void* d_out, int out_size, void* d_ws,
                              size_t ws_size, hipStream_t stream) {
  const float* em = (const float*)d_in[0];
  const int* lens = (const int*)d_in[1];
  const float* trans = (const float*)d_in[2];
  const float* head = (const float*)d_in[3];
  const float* last = (const float*)d_in[4];
  float* out = (float*)d_out;
  uint32_t* ws = (uint32_t*)d_ws;  // 2048*64*128 bf16 = 32 MiB

  eem_prepass<<<8192, 256, 0, stream>>>(em, ws);
  crf_scan_kernel<<<8, 512, 0, stream>>>(em, lens, trans, head, last, ws);
  crf_combine<<<1, 256, 0, stream>>>(out);
}